// Round 1
// 159.654 us; speedup vs baseline: 1.0117x; 1.0117x over previous
//
#include <hip/hip_runtime.h>
#include <hip/hip_bf16.h>

#define N_NODES 8192
#define E_EDGES 16384
#define S_SEG   16
#define EXT     64
#define P_PATHS 2048
#define ROW     1024            // S_SEG*EXT floats per row
#define L_SLOTS 8               // edge slots per slot-group
#define NGROUPS (E_EDGES / L_SLOTS)   // 2048 slot-groups
#define NWAVES  (NGROUPS * 2)         // 4096 waves: 2 channel-halves per group
#define NBLK    (NWAVES / 4)          // 1024 blocks x 4 waves

typedef _Float16 f16x8  __attribute__((ext_vector_type(8)));
typedef _Float16 f16x4  __attribute__((ext_vector_type(4)));
typedef _Float16 half2v __attribute__((ext_vector_type(2)));
typedef float    f32x4  __attribute__((ext_vector_type(4)));

// ---- workspace layout (bytes) ----
#define WS_CMAT  0        // f16[4096]   8 KB
#define WS_HIST  8192     // int[8192]
#define WS_CURS  40960    // int[8192]
#define WS_ROWS  73728    // int[8193]
#define WS_ELIST 106512   // int[16384]
#define WS_XRS   172048   // int[16384]  gather row per sorted slot
#define WS_NDS   237584   // int[16384]  output node per sorted slot

// ---------------------------------------------------------------------------
__global__ void prep(const int* __restrict__ pidx, const float* __restrict__ pcoef,
                     _Float16* __restrict__ Cmat, int* __restrict__ hist) {
    const int tid = threadIdx.x;
    if (blockIdx.x < 32) { hist[blockIdx.x * 256 + tid] = 0; return; }
    __shared__ float sC[S_SEG * S_SEG * S_SEG];
    for (int i = tid; i < 4096; i += 256) sC[i] = 0.f;
    __syncthreads();
    for (int p = tid; p < P_PATHS; p += 256) {
        int i = pidx[3 * p + 0];
        int j = pidx[3 * p + 1];
        int k = pidx[3 * p + 2];
        atomicAdd(&sC[(k * S_SEG + i) * S_SEG + j], pcoef[p]);
    }
    __syncthreads();
    for (int i = tid; i < 4096; i += 256) Cmat[i] = (_Float16)sC[i];
}

__global__ void hist_k(const int* __restrict__ idx_out, int* __restrict__ hist) {
    const int e = blockIdx.x * 256 + threadIdx.x;
    atomicAdd(&hist[idx_out[e]], 1);
}

__global__ __launch_bounds__(256) void scan_k(const int* __restrict__ hist,
                                              int* __restrict__ rows,
                                              int* __restrict__ cursor) {
    __shared__ int part[256];
    const int t = threadIdx.x;
    const int base = t * 32;
    int loc[32];
    int s = 0;
#pragma unroll
    for (int i = 0; i < 32; ++i) { loc[i] = s; s += hist[base + i]; }
    part[t] = s;
    __syncthreads();
    for (int off = 1; off < 256; off <<= 1) {
        int v = part[t];
        int u = (t >= off) ? part[t - off] : 0;
        __syncthreads();
        part[t] = v + u;
        __syncthreads();
    }
    const int excl = (t == 0) ? 0 : part[t - 1];
#pragma unroll
    for (int i = 0; i < 32; ++i) {
        int v = excl + loc[i];
        rows[base + i] = v;
        cursor[base + i] = v;
    }
    if (t == 255) rows[N_NODES] = part[255];
}

// fused: scatter edges into sorted slot arrays + zero-fill tiles of deg-0 /
// group-boundary-crossing nodes.  Both depend only on scan_k.
__global__ __launch_bounds__(256) void scatter_zero_k(
        const int* __restrict__ idx_in, const int* __restrict__ idx_out,
        int* __restrict__ cursor, int* __restrict__ elist,
        int* __restrict__ xrs, int* __restrict__ nds,
        const int* __restrict__ rows, float* __restrict__ out) {
    const int b = blockIdx.x;
    if (b < E_EDGES / 256) {
        const int e = b * 256 + threadIdx.x;
        const int nd = idx_out[e];
        const int pos = atomicAdd(&cursor[nd], 1);
        elist[pos] = e;
        xrs[pos]   = idx_in[e];
        nds[pos]   = nd;
    } else {
        const int n = (b - E_EDGES / 256) * 4 + (threadIdx.x >> 6);
        const int lane = threadIdx.x & 63;
        const int beg = rows[n], end = rows[n + 1];
        const bool need = (beg == end) || ((beg / L_SLOTS) != ((end - 1) / L_SLOTS));
        if (!need) return;
        const float4 z = {0.f, 0.f, 0.f, 0.f};
        float* ob = out + (size_t)n * ROW + lane * 4;
#pragma unroll
        for (int r = 0; r < 4; ++r) *(float4*)(ob + r * 256) = z;
    }
}

// ---------------------------------------------------------------------------
// main: each slot-group of 8 sorted edges is handled by TWO waves, one per
// 32-channel half (disjoint output columns -> boundary logic unchanged).
// Depth-2 register prefetch of the gathered x row-slice and y row-slice;
// fp16 MFMA (16x16x32); plain store for fully-owned nodes, atomicAdd onto
// zeroed background for group-boundary nodes.
// ---------------------------------------------------------------------------
__global__ __launch_bounds__(256, 4) void seg_poly_slots(
        const float* __restrict__ x, const float* __restrict__ y,
        const _Float16* __restrict__ Cmat,
        const int* __restrict__ elist, const int* __restrict__ xrs,
        const int* __restrict__ nds, float* __restrict__ out) {
    __shared__ __attribute__((aligned(16))) _Float16 sx_all[4][S_SEG * 32]; // 1KB/wave
    __shared__ __attribute__((aligned(16))) half2v   sy_all[4][8 * 32];     // 1KB/wave

    const int tid  = threadIdx.x;
    const int lane = tid & 63;
    const int wv   = tid >> 6;
    _Float16* sxh = sx_all[wv];
    half2v*   syp = sy_all[wv];

    const int wid = blockIdx.x * 4 + wv;     // 0..4095
    const int g   = wid >> 1;                // slot-group 0..2047
    const int h   = wid & 1;                 // channel half 0..1
    const int s0  = g * L_SLOTS;
    const int c0  = h * 32;

    const int quad = lane >> 4;
    const int m    = lane & 15;
    const int jb2  = (quad & 1) * 4;
    const int ih   = quad >> 1;
    const int jp   = lane >> 3;          // 0..7 : j-pair index / x segment
    const int c4   = (lane & 7) * 4;     // 4 channels per lane within the half

    // per-slot metadata (wave-uniform)
    int e_[L_SLOTS], xr_[L_SLOTS], nd_[L_SLOTS];
    {
        int4 a = *(const int4*)(elist + s0); int4 b = *(const int4*)(elist + s0 + 4);
        e_[0]=a.x; e_[1]=a.y; e_[2]=a.z; e_[3]=a.w; e_[4]=b.x; e_[5]=b.y; e_[6]=b.z; e_[7]=b.w;
        a = *(const int4*)(xrs + s0); b = *(const int4*)(xrs + s0 + 4);
        xr_[0]=a.x; xr_[1]=a.y; xr_[2]=a.z; xr_[3]=a.w; xr_[4]=b.x; xr_[5]=b.y; xr_[6]=b.z; xr_[7]=b.w;
        a = *(const int4*)(nds + s0); b = *(const int4*)(nds + s0 + 4);
        nd_[0]=a.x; nd_[1]=a.y; nd_[2]=a.z; nd_[3]=a.w; nd_[4]=b.x; nd_[5]=b.y; nd_[6]=b.z; nd_[7]=b.w;
    }
    const bool prev_same = (s0 > 0)                  && (nds[s0 - 1]       == nd_[0]);
    const bool next_same = (s0 + L_SLOTS < E_EDGES)  && (nds[s0 + L_SLOTS] == nd_[L_SLOTS - 1]);

    // A fragments (constant, channel-independent): afrag[kk][jr] = Cmat[m][kk*32 + quad*8 + jr]
    f16x8 afrag[8];
    {
        const _Float16* basep = Cmat + m * 256 + quad * 8;
#pragma unroll
        for (int kk = 0; kk < 8; ++kk) afrag[kk] = *(const f16x8*)(basep + kk * 32);
    }

    // register prefetch buffers: per edge, 2 float4 of x-slice + 2 float4 of y-slice
    float4 xbuf[2][2], ybuf[2][2];
    auto issue = [&](int t, int b) {
        const float* xp = x + (size_t)xr_[t] * ROW + c0;
        const float* yp = y + (size_t)e_[t] * ROW + c0;
        xbuf[b][0] = *(const float4*)(xp + jp * EXT + c4);          // segs 0..7
        xbuf[b][1] = *(const float4*)(xp + (jp + 8) * EXT + c4);    // segs 8..15
        ybuf[b][0] = *(const float4*)(yp + (2 * jp)     * EXT + c4);
        ybuf[b][1] = *(const float4*)(yp + (2 * jp + 1) * EXT + c4);
    };
    issue(0, 0);
    issue(1, 1);

    f32x4 acc[2];
#pragma unroll
    for (int ct = 0; ct < 2; ++ct) acc[ct] = f32x4{0.f, 0.f, 0.f, 0.f};
    int segStart = 0;

#pragma unroll
    for (int t = 0; t < L_SLOTS; ++t) {
        const int b = t & 1;

        // stage current edge regs -> f16 LDS (wave-private, no barriers)
        {
            const float4 v0 = xbuf[b][0], v1 = xbuf[b][1];
            *(f16x4*)(sxh + jp * 32 + c4) =
                f16x4{(_Float16)v0.x, (_Float16)v0.y, (_Float16)v0.z, (_Float16)v0.w};
            *(f16x4*)(sxh + (jp + 8) * 32 + c4) =
                f16x4{(_Float16)v1.x, (_Float16)v1.y, (_Float16)v1.z, (_Float16)v1.w};
            const float4 a0 = ybuf[b][0], a1 = ybuf[b][1];
            *(f16x8*)(syp + jp * 32 + c4) =
                f16x8{(_Float16)a0.x, (_Float16)a1.x, (_Float16)a0.y, (_Float16)a1.y,
                      (_Float16)a0.z, (_Float16)a1.z, (_Float16)a0.w, (_Float16)a1.w};
        }
        if (t + 2 < L_SLOTS) issue(t + 2, b);   // depth-2 prefetch into freed slot

        // compute: 2 col-tiles (this half) x 8 K-steps of mfma_f32_16x16x32_f16
#pragma unroll
        for (int ct = 0; ct < 2; ++ct) {
            const int cl = ct * 16 + m;          // channel within the half
            half2v ypk[4];
#pragma unroll
            for (int r = 0; r < 4; ++r) ypk[r] = syp[(jb2 + r) * 32 + cl];
#pragma unroll
            for (int kk = 0; kk < 8; ++kk) {
                const _Float16 xh = sxh[(2 * kk + ih) * 32 + cl];
                const half2v hx = {xh, xh};
                const half2v b0 = hx * ypk[0];
                const half2v b1 = hx * ypk[1];
                const half2v b2 = hx * ypk[2];
                const half2v b3 = hx * ypk[3];
                const f16x8 bfrag = {b0[0], b0[1], b1[0], b1[1],
                                     b2[0], b2[1], b3[0], b3[1]};
                acc[ct] = __builtin_amdgcn_mfma_f32_16x16x32_f16(
                              afrag[kk], bfrag, acc[ct], 0, 0, 0);
            }
        }

        // flush at node boundary
        const bool last = (t == L_SLOTS - 1);
        if (last || nd_[t + 1] != nd_[t]) {
            const bool shared = (segStart == 0 && prev_same) || (last && next_same);
            float* ob = out + (size_t)nd_[t] * ROW + c0;
            if (shared) {
#pragma unroll
                for (int ct = 0; ct < 2; ++ct)
#pragma unroll
                    for (int r = 0; r < 4; ++r)
                        atomicAdd(ob + (quad * 4 + r) * EXT + ct * 16 + m, acc[ct][r]);
            } else {
#pragma unroll
                for (int ct = 0; ct < 2; ++ct)
#pragma unroll
                    for (int r = 0; r < 4; ++r)
                        ob[(quad * 4 + r) * EXT + ct * 16 + m] = acc[ct][r];
            }
#pragma unroll
            for (int ct = 0; ct < 2; ++ct) acc[ct] = f32x4{0.f, 0.f, 0.f, 0.f};
            segStart = t + 1;
        }
    }
}

extern "C" void kernel_launch(void* const* d_in, const int* in_sizes, int n_in,
                              void* d_out, int out_size, void* d_ws, size_t ws_size,
                              hipStream_t stream) {
    const float* x       = (const float*)d_in[0];
    const float* y       = (const float*)d_in[1];
    const int*   idx_in  = (const int*)d_in[2];
    const int*   idx_out = (const int*)d_in[3];
    const int*   pidx    = (const int*)d_in[4];
    const float* pcoef   = (const float*)d_in[5];
    float* out           = (float*)d_out;

    char* ws = (char*)d_ws;
    _Float16* Cmat = (_Float16*)(ws + WS_CMAT);
    int* hist      = (int*)(ws + WS_HIST);
    int* cursor    = (int*)(ws + WS_CURS);
    int* rows      = (int*)(ws + WS_ROWS);
    int* elist     = (int*)(ws + WS_ELIST);
    int* xrs       = (int*)(ws + WS_XRS);
    int* nds       = (int*)(ws + WS_NDS);

    prep<<<33, 256, 0, stream>>>(pidx, pcoef, Cmat, hist);
    hist_k<<<E_EDGES / 256, 256, 0, stream>>>(idx_out, hist);
    scan_k<<<1, 256, 0, stream>>>(hist, rows, cursor);
    scatter_zero_k<<<E_EDGES / 256 + N_NODES / 4, 256, 0, stream>>>(
        idx_in, idx_out, cursor, elist, xrs, nds, rows, out);
    seg_poly_slots<<<NBLK, 256, 0, stream>>>(x, y, Cmat, elist, xrs, nds, out);
}